// Round 2
// baseline (306.814 us; speedup 1.0000x reference)
//
#include <hip/hip_runtime.h>
#include <hip/hip_cooperative_groups.h>
#include <math.h>

namespace cg = cooperative_groups;

// AdaptiveSelection on MI355X (gfx950)
// Inputs (fp32): cluster_features (8,4096,1024), key_feats (8,1,1024),
//                q_w (128,1024), q_b (128), v_w (1024,1024), v_b (1024)
// Outputs (fp32, concat): selected (1024,1024) then fus (8,1024)
//
// Algebra:
//   logit_i = f_i . w_c where w_c = q_w^T (q_w key_c + q_b)/sqrt(128) (+const, dropped)
//   topk-128 by logit == topk by softmax (monotone)
//   fusion = v_w @ (A^T feats) + v_b     (sum A = 1)
// Ranking: 64-bit sortable key (ordered float bits << 32 | ~index) makes the
// reference's (value desc, index asc) order a single unsigned compare.
// Top-128 via per-cluster in-LDS radix select (32KB keys fit in one block).
// 3 dispatches: k0 -> k1 -> cooperative fat_ab
//   fat_ab phase A: blocks 0..127 combine (16 blocks/cluster), 128..135 select,
//                   136..255 prefetch their v_w rows into registers.
//   grid.sync()
//   fat_ab phase B: blocks 0..127 gather, 128..255 k5 fusion GEMV.

#define DIM   1024
#define NC    8
#define NPER  4096
#define QD    128
#define TOPK  128
#define K1B   128     // blocks per cluster in main streaming pass (4 blocks/CU)

typedef unsigned long long u64;
typedef __attribute__((ext_vector_type(2))) unsigned long long ull2;
typedef __attribute__((ext_vector_type(4))) float f4;   // for nontemporal ld/st

// ---------------- K0: fused prep -> w_all (8,1024) ----------------
__global__ __launch_bounds__(256) void k0_prep(
    const float* __restrict__ key_feats, const float* __restrict__ q_w,
    const float* __restrict__ q_b, float* __restrict__ w_all)
{
    const int c  = blockIdx.x >> 2, jc = blockIdx.x & 3;
    const int tid = threadIdx.x;
    __shared__ float part[256];
    __shared__ float qs[QD];

    {   // phase 1: qk[k] = dot(q_w[k], key_c) + q_b[k]; 2 threads per k
        const int k = tid >> 1, half = tid & 1;
        const float4* qr4 = (const float4*)(q_w + (size_t)k * DIM + half * 512);
        const float4* kf4 = (const float4*)(key_feats + (size_t)c * DIM + half * 512);
        float s = 0.f;
        #pragma unroll 16
        for (int j = 0; j < 128; ++j) {
            float4 a = qr4[j], b = kf4[j];
            s += a.x*b.x + a.y*b.y + a.z*b.z + a.w*b.w;
        }
        part[tid] = s;
    }
    __syncthreads();
    if (tid < QD) qs[tid] = part[2*tid] + part[2*tid+1] + q_b[tid];
    __syncthreads();

    // phase 2: w[j] = sum_k q_w[k][j] * qs[k] / sqrt(128)
    const int j = jc * 256 + tid;
    float s = 0.f;
    #pragma unroll 16
    for (int k = 0; k < QD; ++k)
        s += q_w[(size_t)k * DIM + j] * qs[k];
    w_all[c * DIM + j] = s * 0.08838834764831845f; // 1/sqrt(128)
}

// ---------------- K1: fused logits(keys) + online-softmax weighted row sum ----------
// feats stream via nontemporal loads (read-once; keep L2 for pacc/keys).
__global__ __launch_bounds__(256, 4) void k1_main(
    const float* __restrict__ feats, const float* __restrict__ w_all,
    u64* __restrict__ keys,            // (8,4096) sortable keys
    float* __restrict__ pacc,          // (8*K1B,1024)
    float* __restrict__ pm, float* __restrict__ pz)  // (8*K1B)
{
    const int c    = blockIdx.y;
    const int blk  = blockIdx.x;
    const int tid  = threadIdx.x;
    const int lane = tid & 63;
    const int wave = tid >> 6;

    const float4* w4 = (const float4*)(w_all + c * DIM);
    float4 wv[4];
    #pragma unroll
    for (int q = 0; q < 4; ++q) wv[q] = w4[lane + 64*q];

    float4 acc[4];
    #pragma unroll
    for (int q = 0; q < 4; ++q) acc[q] = make_float4(0.f, 0.f, 0.f, 0.f);
    float m = -INFINITY, Z = 0.f;

    const int wslot = blk * 4 + wave;          // 0..511
    const float* fc = feats + (size_t)c * NPER * DIM;

    f4 fA[4], fB[4];
    {
        const f4* f4p = (const f4*)(fc + (size_t)wslot * DIM);
        #pragma unroll
        for (int q = 0; q < 4; ++q) fA[q] = __builtin_nontemporal_load(f4p + lane + 64*q);
    }

    #define K1_PROCESS(FREG, ROW)                                              \
    do {                                                                       \
        float p = 0.f;                                                         \
        _Pragma("unroll")                                                      \
        for (int q = 0; q < 4; ++q)                                            \
            p += FREG[q].x*wv[q].x + FREG[q].y*wv[q].y +                       \
                 FREG[q].z*wv[q].z + FREG[q].w*wv[q].w;                        \
        _Pragma("unroll")                                                      \
        for (int off = 32; off > 0; off >>= 1) p += __shfl_xor(p, off, 64);    \
        if (lane == 0) {                                                       \
            unsigned int b = __float_as_uint(p);                               \
            unsigned int u = b ^ ((b & 0x80000000u) ? 0xFFFFFFFFu : 0x80000000u); \
            keys[c * NPER + (ROW)] = ((u64)u << 32) | (unsigned int)(~(ROW));  \
        }                                                                      \
        if (p > m) {   /* wave-uniform; rare after first rows */               \
            const float sOld = __expf(m - p);                                  \
            Z = Z * sOld + 1.f;                                                \
            _Pragma("unroll")                                                  \
            for (int q = 0; q < 4; ++q) {                                      \
                acc[q].x = acc[q].x * sOld + FREG[q].x;                        \
                acc[q].y = acc[q].y * sOld + FREG[q].y;                        \
                acc[q].z = acc[q].z * sOld + FREG[q].z;                        \
                acc[q].w = acc[q].w * sOld + FREG[q].w;                        \
            }                                                                  \
            m = p;                                                             \
        } else {                                                               \
            const float t = __expf(p - m);                                     \
            Z += t;                                                            \
            _Pragma("unroll")                                                  \
            for (int q = 0; q < 4; ++q) {                                      \
                acc[q].x += t * FREG[q].x;                                     \
                acc[q].y += t * FREG[q].y;                                     \
                acc[q].z += t * FREG[q].z;                                     \
                acc[q].w += t * FREG[q].w;                                     \
            }                                                                  \
        }                                                                      \
    } while (0)

    for (int it = 0; it < 8; it += 2) {
        const int r0 = wslot + 512 * it;
        {   // prefetch next row
            const f4* f4p = (const f4*)(fc + (size_t)(r0 + 512) * DIM);
            #pragma unroll
            for (int q = 0; q < 4; ++q) fB[q] = __builtin_nontemporal_load(f4p + lane + 64*q);
        }
        K1_PROCESS(fA, r0);
        if (it + 2 < 8) {
            const f4* f4p = (const f4*)(fc + (size_t)(r0 + 1024) * DIM);
            #pragma unroll
            for (int q = 0; q < 4; ++q) fA[q] = __builtin_nontemporal_load(f4p + lane + 64*q);
        }
        K1_PROCESS(fB, r0 + 512);
    }
    #undef K1_PROCESS

    __shared__ float sm[4], sz[4];
    __shared__ float sacc[4][DIM];
    if (lane == 0) { sm[wave] = m; sz[wave] = Z; }
    #pragma unroll
    for (int q = 0; q < 4; ++q)
        ((float4*)sacc[wave])[lane + 64*q] = acc[q];
    __syncthreads();

    const float mb = fmaxf(fmaxf(sm[0], sm[1]), fmaxf(sm[2], sm[3]));
    const float e0 = __expf(sm[0] - mb), e1 = __expf(sm[1] - mb);
    const float e2 = __expf(sm[2] - mb), e3 = __expf(sm[3] - mb);
    float4 a0 = ((float4*)sacc[0])[tid];
    float4 a1 = ((float4*)sacc[1])[tid];
    float4 a2 = ((float4*)sacc[2])[tid];
    float4 a3 = ((float4*)sacc[3])[tid];
    float4 o;
    o.x = a0.x*e0 + a1.x*e1 + a2.x*e2 + a3.x*e3;
    o.y = a0.y*e0 + a1.y*e1 + a2.y*e2 + a3.y*e3;
    o.z = a0.z*e0 + a1.z*e1 + a2.z*e2 + a3.z*e3;
    o.w = a0.w*e0 + a1.w*e1 + a2.w*e2 + a3.w*e3;
    ((float4*)(pacc + (size_t)(c * K1B + blk) * DIM))[tid] = o;
    if (tid == 0) {
        pm[c * K1B + blk] = mb;
        pz[c * K1B + blk] = sz[0]*e0 + sz[1]*e1 + sz[2]*e2 + sz[3]*e3;
    }
}

// ---------------- FAT AB (cooperative, 256 blocks) ----------------
// Phase A: blocks 0..127 combine (c = b>>4, 64 j-floats each)
//          blocks 128..135 per-cluster radix select -> selIdx
//          blocks 136..255 prefetch their v_w rows into registers
// grid.sync()
// Phase B: blocks 0..127 gather selected rows; blocks 128..255 k5 fusion.
__global__ __launch_bounds__(256) void fat_ab(
    const float* __restrict__ pacc, const float* __restrict__ pm,
    const float* __restrict__ pz, float* __restrict__ g,
    const u64* __restrict__ keys, int* __restrict__ selIdx,
    const float* __restrict__ feats, float* __restrict__ out_sel,
    const float* __restrict__ v_w, const float* __restrict__ v_b,
    float* __restrict__ fus)
{
    const int bid = blockIdx.x;
    const int tid = threadIdx.x;
    // 58384-byte LDS overlay (select is the largest user; k5 reuses 32KB)
    __shared__ float4 shraw4[3649];

    // --- v_w register prefetch for k5 blocks not busy with select ---
    float4 vpre0[4], vpre1[4];
    const bool kpre = (bid >= 136);
    if (kpre) {
        const int lane = tid & 63, wave = tid >> 6;
        const int row0 = (bid - 128) * 8 + wave * 2;
        const float4* vr0 = (const float4*)(v_w + (size_t)row0 * DIM);
        const float4* vr1 = (const float4*)(v_w + (size_t)(row0 + 1) * DIM);
        #pragma unroll
        for (int u = 0; u < 4; ++u) { vpre0[u] = vr0[lane + 64*u]; vpre1[u] = vr1[lane + 64*u]; }
    }

    if (bid < 128) {
        // ---- combine: g_c[j] = (1/Z_c) sum_b swe[b] * pacc[c,b,j] ----
        const int c = bid >> 4, jb = bid & 15;         // 64 floats per block
        float* spm = (float*)shraw4;                   // 128
        float* spz = spm + 128;                        // 128
        float* swe = spz + 128;                        // 128
        float* szc = swe + 128;                        // 1 (+3 pad)
        float4* sred = (float4*)(szc + 4);             // [16 bg][16 col]

        if (tid < K1B)       spm[tid]       = pm[c*K1B + tid];
        else                 spz[tid - K1B] = pz[c*K1B + tid - K1B];
        __syncthreads();
        float mc = -INFINITY;
        for (int b = 0; b < K1B; ++b) mc = fmaxf(mc, spm[b]);
        if (tid < K1B) swe[tid] = __expf(spm[tid] - mc);
        __syncthreads();
        if (tid == 0) {
            float z = 0.f;
            for (int b = 0; b < K1B; ++b) z += spz[b] * swe[b];
            *szc = z;
        }
        const int col = tid & 15;       // float4 column within 64-float slice
        const int bg  = tid >> 4;       // 16 groups of 8 partials
        const int jbase = jb * 64 + col * 4;
        float4 a = make_float4(0.f, 0.f, 0.f, 0.f);
        #pragma unroll
        for (int k = 0; k < 8; ++k) {
            const int b = bg * 8 + k;
            const float e = swe[b];
            float4 v = *(const float4*)(pacc + (size_t)(c*K1B + b) * DIM + jbase);
            a.x += e*v.x; a.y += e*v.y; a.z += e*v.z; a.w += e*v.w;
        }
        sred[bg * 16 + col] = a;
        __syncthreads();
        if (tid < 16) {
            float4 o = make_float4(0.f, 0.f, 0.f, 0.f);
            #pragma unroll
            for (int gg = 0; gg < 16; ++gg) {
                float4 t = sred[gg * 16 + tid];
                o.x += t.x; o.y += t.y; o.z += t.z; o.w += t.w;
            }
            const float inv = 1.0f / (*szc);
            o.x *= inv; o.y *= inv; o.z *= inv; o.w *= inv;
            *(float4*)(g + c * DIM + jb * 64 + tid * 4) = o;
        }
    } else if (bid < 136) {
        // ---- select: per-cluster top-128 with exact ranks, all in LDS ----
        const int c = bid - 128;
        u64* lk = (u64*)shraw4;                              // 32 KB
        int* hist = (int*)(lk + NPER);                       // 16 KB
        unsigned short* cand = (unsigned short*)(hist + 4096); // 8 KB
        int* chunkSuf = (int*)(cand + NPER);                 // 1 KB
        int* critBin = chunkSuf + 256;
        int* candCnt = critBin + 1;

        for (int t = tid; t < NPER/2; t += 256)
            ((ull2*)lk)[t] = ((const ull2*)(keys + (size_t)c * NPER))[t];
        for (int t = tid; t < 4096; t += 256) hist[t] = 0;
        if (tid == 0) *candCnt = 0;
        __syncthreads();

        // histogram on key bits [63:52] (= top 12 bits of ordered float)
        #pragma unroll
        for (int q = 0; q < 16; ++q)
            atomicAdd(&hist[(int)(lk[tid + 256*q] >> 52)], 1);
        __syncthreads();

        {   // per-thread chunk sums (16 bins each)
            int s = 0;
            #pragma unroll
            for (int b = 0; b < 16; ++b) s += hist[tid*16 + b];
            chunkSuf[tid] = s;
        }
        __syncthreads();
        if (tid == 0) {   // serial suffix over 256 chunks (high->low)
            int run = 0;
            for (int t = 255; t >= 0; --t) {
                const int v = chunkSuf[t]; chunkSuf[t] = run; run += v;
            }
        }
        __syncthreads();
        {   // find critical bin B: above(B) < TOPK <= above(B)+hist[B]
            int run = chunkSuf[tid];             // keys in bins above my chunk
            for (int b = 15; b >= 0; --b) {
                const int bin = tid*16 + b;
                const int h = hist[bin];
                if (run < TOPK && run + h >= TOPK) *critBin = bin; // one hit
                run += h;
            }
        }
        __syncthreads();
        const int B = *critBin;

        // compact candidate set = all keys in bins >= B
        #pragma unroll
        for (int q = 0; q < 16; ++q) {
            const int i = tid + 256*q;
            if ((int)(lk[i] >> 52) >= B) {
                const int s = atomicAdd(candCnt, 1);
                cand[s] = (unsigned short)i;
            }
        }
        __syncthreads();

        // exact global rank via pairwise compare within candidate set
        const int M = *candCnt;
        for (int s = tid; s < M; s += 256) {
            const int i = (int)cand[s];
            const u64 ki = lk[i];
            int r = 0;
            for (int j = 0; j < M; ++j)
                r += (lk[(int)cand[j]] > ki) ? 1 : 0;
            if (r < TOPK) selIdx[c * TOPK + r] = i;
        }
    }

    __threadfence();                 // make g / selIdx device-visible
    cg::this_grid().sync();

    if (bid < 128) {
        // ---- gather: 8 ranked rows per block, software-pipelined copy ----
        const int c  = bid >> 4;
        const int r0 = (bid & 15) * 8;
        const float* fc = feats + (size_t)c * NPER * DIM;
        const int* sic = selIdx + c * TOPK + r0;

        f4 cur = __builtin_nontemporal_load(
            (const f4*)(fc + (size_t)sic[0] * DIM) + tid);
        #pragma unroll
        for (int s = 0; s < 8; ++s) {
            f4 nxt;
            if (s + 1 < 8)
                nxt = __builtin_nontemporal_load(
                    (const f4*)(fc + (size_t)sic[s+1] * DIM) + tid);
            __builtin_nontemporal_store(
                cur, (f4*)(out_sel + ((size_t)c * TOPK + r0 + s) * DIM) + tid);
            if (s + 1 < 8) cur = nxt;
        }
    } else {
        // ---- k5: fus = v_w @ g + v_b, one pass over v_w ----
        float4* sg = shraw4;                        // [NC][256] float4 = 32 KB
        const int lane = tid & 63, wave = tid >> 6;
        __syncthreads();                            // select/combine done w/ LDS
        for (int t = tid; t < NC * 256; t += 256)
            sg[t] = ((const float4*)g)[t];
        __syncthreads();

        const int row0 = (bid - 128) * 8 + wave * 2;
        #pragma unroll
        for (int rr = 0; rr < 2; ++rr) {
            const int o = row0 + rr;
            float4 v[4];
            if (kpre) {
                #pragma unroll
                for (int u = 0; u < 4; ++u) v[u] = rr ? vpre1[u] : vpre0[u];
            } else {
                const float4* vr = (const float4*)(v_w + (size_t)o * DIM);
                #pragma unroll
                for (int u = 0; u < 4; ++u) v[u] = vr[lane + 64*u];
            }
            float p[NC];
            #pragma unroll
            for (int cc = 0; cc < NC; ++cc) {
                float s = 0.f;
                #pragma unroll
                for (int u = 0; u < 4; ++u) {
                    float4 gv = sg[cc * 256 + lane + 64*u];
                    s += v[u].x*gv.x + v[u].y*gv.y + v[u].z*gv.z + v[u].w*gv.w;
                }
                p[cc] = s;
            }
            #pragma unroll
            for (int off = 32; off > 0; off >>= 1) {
                #pragma unroll
                for (int cc = 0; cc < NC; ++cc) p[cc] += __shfl_xor(p[cc], off, 64);
            }
            if (lane == 0) {
                const float b = v_b[o];
                #pragma unroll
                for (int cc = 0; cc < NC; ++cc) fus[cc * DIM + o] = p[cc] + b;
            }
        }
    }
}

extern "C" void kernel_launch(void* const* d_in, const int* in_sizes, int n_in,
                              void* d_out, int out_size, void* d_ws, size_t ws_size,
                              hipStream_t stream) {
    const float* feats     = (const float*)d_in[0];
    const float* key_feats = (const float*)d_in[1];
    const float* q_w       = (const float*)d_in[2];
    const float* q_b       = (const float*)d_in[3];
    const float* v_w       = (const float*)d_in[4];
    const float* v_b       = (const float*)d_in[5];
    float* out      = (float*)d_out;
    float* out_sel  = out;
    float* out_fus  = out + (size_t)1024 * 1024;

    // workspace layout (8B-aligned first)
    u64*   keys   = (u64*)d_ws;                          // 256 KB
    float* pacc   = (float*)(keys + NC * NPER);          // 4 MB
    float* pm     = pacc + (size_t)NC * K1B * DIM;       // 1024
    float* pz     = pm + NC * K1B;                       // 1024
    float* g      = pz + NC * K1B;                       // 8*1024
    float* w_all  = g + NC * DIM;                        // 8*1024
    int*   selIdx = (int*)(w_all + NC * DIM);            // 8*128 ints = 4 KB

    k0_prep <<<dim3(NC * 4),  256, 0, stream>>>(key_feats, q_w, q_b, w_all);
    k1_main <<<dim3(K1B, NC), 256, 0, stream>>>(feats, w_all, keys, pacc, pm, pz);

    void* args[] = { (void*)&pacc, (void*)&pm, (void*)&pz, (void*)&g,
                     (void*)&keys, (void*)&selIdx, (void*)&feats,
                     (void*)&out_sel, (void*)&v_w, (void*)&v_b, (void*)&out_fus };
    hipLaunchCooperativeKernel(fat_ab, dim3(256), dim3(256), args, 0, stream);
}

// Round 3
// 237.509 us; speedup vs baseline: 1.2918x; 1.2918x over previous
//
#include <hip/hip_runtime.h>
#include <math.h>

// AdaptiveSelection on MI355X (gfx950)
// Inputs (fp32): cluster_features (8,4096,1024), key_feats (8,1,1024),
//                q_w (128,1024), q_b (128), v_w (1024,1024), v_b (1024)
// Outputs (fp32, concat): selected (1024,1024) then fus (8,1024)
//
// Algebra:
//   logit_i = f_i . w_c where w_c = q_w^T (q_w key_c + q_b)/sqrt(128) (+const, dropped)
//   topk-128 by logit == topk by softmax (monotone)
//   fusion = v_w @ (A^T feats) + v_b     (sum A = 1)
// Ranking: 64-bit sortable key (ordered float bits << 32 | ~index) makes the
// reference's (value desc, index asc) order a single unsigned compare.
// Top-128 via per-cluster in-LDS radix select (32KB keys fit in one block).
// R2 post-mortem: hipLaunchCooperativeKernel cost ~70us in this harness ->
// reverted to 4 ordinary dispatches; kept the widened combine (128 blocks).
// Dispatches: k0 -> k1 -> fat_a(combine 128 | select 8) -> fat_b(gather|k5).

#define DIM   1024
#define NC    8
#define NPER  4096
#define QD    128
#define TOPK  128
#define K1B   128     // blocks per cluster in main streaming pass (4 blocks/CU)

typedef unsigned long long u64;
typedef __attribute__((ext_vector_type(2))) unsigned long long ull2;
typedef __attribute__((ext_vector_type(4))) float f4;   // for nontemporal ld/st

// ---------------- K0: fused prep -> w_all (8,1024) ----------------
__global__ __launch_bounds__(256) void k0_prep(
    const float* __restrict__ key_feats, const float* __restrict__ q_w,
    const float* __restrict__ q_b, float* __restrict__ w_all)
{
    const int c  = blockIdx.x >> 2, jc = blockIdx.x & 3;
    const int tid = threadIdx.x;
    __shared__ float part[256];
    __shared__ float qs[QD];

    {   // phase 1: qk[k] = dot(q_w[k], key_c) + q_b[k]; 2 threads per k
        const int k = tid >> 1, half = tid & 1;
        const float4* qr4 = (const float4*)(q_w + (size_t)k * DIM + half * 512);
        const float4* kf4 = (const float4*)(key_feats + (size_t)c * DIM + half * 512);
        float s = 0.f;
        #pragma unroll 16
        for (int j = 0; j < 128; ++j) {
            float4 a = qr4[j], b = kf4[j];
            s += a.x*b.x + a.y*b.y + a.z*b.z + a.w*b.w;
        }
        part[tid] = s;
    }
    __syncthreads();
    if (tid < QD) qs[tid] = part[2*tid] + part[2*tid+1] + q_b[tid];
    __syncthreads();

    // phase 2: w[j] = sum_k q_w[k][j] * qs[k] / sqrt(128)
    const int j = jc * 256 + tid;
    float s = 0.f;
    #pragma unroll 16
    for (int k = 0; k < QD; ++k)
        s += q_w[(size_t)k * DIM + j] * qs[k];
    w_all[c * DIM + j] = s * 0.08838834764831845f; // 1/sqrt(128)
}

// ---------------- K1: fused logits(keys) + online-softmax weighted row sum ----------
// feats stream via nontemporal loads (read-once; keep L2 for pacc/keys).
__global__ __launch_bounds__(256, 4) void k1_main(
    const float* __restrict__ feats, const float* __restrict__ w_all,
    u64* __restrict__ keys,            // (8,4096) sortable keys
    float* __restrict__ pacc,          // (8*K1B,1024)
    float* __restrict__ pm, float* __restrict__ pz)  // (8*K1B)
{
    const int c    = blockIdx.y;
    const int blk  = blockIdx.x;
    const int tid  = threadIdx.x;
    const int lane = tid & 63;
    const int wave = tid >> 6;

    const float4* w4 = (const float4*)(w_all + c * DIM);
    float4 wv[4];
    #pragma unroll
    for (int q = 0; q < 4; ++q) wv[q] = w4[lane + 64*q];

    float4 acc[4];
    #pragma unroll
    for (int q = 0; q < 4; ++q) acc[q] = make_float4(0.f, 0.f, 0.f, 0.f);
    float m = -INFINITY, Z = 0.f;

    const int wslot = blk * 4 + wave;          // 0..511
    const float* fc = feats + (size_t)c * NPER * DIM;

    f4 fA[4], fB[4];
    {
        const f4* f4p = (const f4*)(fc + (size_t)wslot * DIM);
        #pragma unroll
        for (int q = 0; q < 4; ++q) fA[q] = __builtin_nontemporal_load(f4p + lane + 64*q);
    }

    #define K1_PROCESS(FREG, ROW)                                              \
    do {                                                                       \
        float p = 0.f;                                                         \
        _Pragma("unroll")                                                      \
        for (int q = 0; q < 4; ++q)                                            \
            p += FREG[q].x*wv[q].x + FREG[q].y*wv[q].y +                       \
                 FREG[q].z*wv[q].z + FREG[q].w*wv[q].w;                        \
        _Pragma("unroll")                                                      \
        for (int off = 32; off > 0; off >>= 1) p += __shfl_xor(p, off, 64);    \
        if (lane == 0) {                                                       \
            unsigned int b = __float_as_uint(p);                               \
            unsigned int u = b ^ ((b & 0x80000000u) ? 0xFFFFFFFFu : 0x80000000u); \
            keys[c * NPER + (ROW)] = ((u64)u << 32) | (unsigned int)(~(ROW));  \
        }                                                                      \
        if (p > m) {   /* wave-uniform; rare after first rows */               \
            const float sOld = __expf(m - p);                                  \
            Z = Z * sOld + 1.f;                                                \
            _Pragma("unroll")                                                  \
            for (int q = 0; q < 4; ++q) {                                      \
                acc[q].x = acc[q].x * sOld + FREG[q].x;                        \
                acc[q].y = acc[q].y * sOld + FREG[q].y;                        \
                acc[q].z = acc[q].z * sOld + FREG[q].z;                        \
                acc[q].w = acc[q].w * sOld + FREG[q].w;                        \
            }                                                                  \
            m = p;                                                             \
        } else {                                                               \
            const float t = __expf(p - m);                                     \
            Z += t;                                                            \
            _Pragma("unroll")                                                  \
            for (int q = 0; q < 4; ++q) {                                      \
                acc[q].x += t * FREG[q].x;                                     \
                acc[q].y += t * FREG[q].y;                                     \
                acc[q].z += t * FREG[q].z;                                     \
                acc[q].w += t * FREG[q].w;                                     \
            }                                                                  \
        }                                                                      \
    } while (0)

    for (int it = 0; it < 8; it += 2) {
        const int r0 = wslot + 512 * it;
        {   // prefetch next row
            const f4* f4p = (const f4*)(fc + (size_t)(r0 + 512) * DIM);
            #pragma unroll
            for (int q = 0; q < 4; ++q) fB[q] = __builtin_nontemporal_load(f4p + lane + 64*q);
        }
        K1_PROCESS(fA, r0);
        if (it + 2 < 8) {
            const f4* f4p = (const f4*)(fc + (size_t)(r0 + 1024) * DIM);
            #pragma unroll
            for (int q = 0; q < 4; ++q) fA[q] = __builtin_nontemporal_load(f4p + lane + 64*q);
        }
        K1_PROCESS(fB, r0 + 512);
    }
    #undef K1_PROCESS

    __shared__ float sm[4], sz[4];
    __shared__ float sacc[4][DIM];
    if (lane == 0) { sm[wave] = m; sz[wave] = Z; }
    #pragma unroll
    for (int q = 0; q < 4; ++q)
        ((float4*)sacc[wave])[lane + 64*q] = acc[q];
    __syncthreads();

    const float mb = fmaxf(fmaxf(sm[0], sm[1]), fmaxf(sm[2], sm[3]));
    const float e0 = __expf(sm[0] - mb), e1 = __expf(sm[1] - mb);
    const float e2 = __expf(sm[2] - mb), e3 = __expf(sm[3] - mb);
    float4 a0 = ((float4*)sacc[0])[tid];
    float4 a1 = ((float4*)sacc[1])[tid];
    float4 a2 = ((float4*)sacc[2])[tid];
    float4 a3 = ((float4*)sacc[3])[tid];
    float4 o;
    o.x = a0.x*e0 + a1.x*e1 + a2.x*e2 + a3.x*e3;
    o.y = a0.y*e0 + a1.y*e1 + a2.y*e2 + a3.y*e3;
    o.z = a0.z*e0 + a1.z*e1 + a2.z*e2 + a3.z*e3;
    o.w = a0.w*e0 + a1.w*e1 + a2.w*e2 + a3.w*e3;
    ((float4*)(pacc + (size_t)(c * K1B + blk) * DIM))[tid] = o;
    if (tid == 0) {
        pm[c * K1B + blk] = mb;
        pz[c * K1B + blk] = sz[0]*e0 + sz[1]*e1 + sz[2]*e2 + sz[3]*e3;
    }
}

// ---------------- FAT A: blocks 0..127 = combine (16/cluster); 128..135 = select ----
__global__ __launch_bounds__(256) void fat_a(
    const float* __restrict__ pacc, const float* __restrict__ pm,
    const float* __restrict__ pz, float* __restrict__ g,
    const u64* __restrict__ keys, int* __restrict__ selIdx) // selIdx (8,128)
{
    const int bid = blockIdx.x;
    const int tid = threadIdx.x;
    // LDS overlay; select is the largest user (~57.4 KB)
    __shared__ float4 shraw4[3649];

    if (bid < 128) {
        // ---- combine: g_c[j] = (1/Z_c) sum_b swe[b] * pacc[c,b,j] ----
        const int c = bid >> 4, jb = bid & 15;         // 64 floats per block
        float* spm = (float*)shraw4;                   // 128
        float* spz = spm + 128;                        // 128
        float* swe = spz + 128;                        // 128
        float* szc = swe + 128;                        // 1 (+3 pad)
        float4* sred = (float4*)(szc + 4);             // [16 bg][16 col]

        if (tid < K1B)       spm[tid]       = pm[c*K1B + tid];
        else                 spz[tid - K1B] = pz[c*K1B + tid - K1B];
        __syncthreads();
        float mc = -INFINITY;
        for (int b = 0; b < K1B; ++b) mc = fmaxf(mc, spm[b]);
        if (tid < K1B) swe[tid] = __expf(spm[tid] - mc);
        __syncthreads();
        if (tid == 0) {
            float z = 0.f;
            for (int b = 0; b < K1B; ++b) z += spz[b] * swe[b];
            *szc = z;
        }
        const int col = tid & 15;       // float4 column within 64-float slice
        const int bg  = tid >> 4;       // 16 groups of 8 partials
        const int jbase = jb * 64 + col * 4;
        float4 a = make_float4(0.f, 0.f, 0.f, 0.f);
        #pragma unroll
        for (int k = 0; k < 8; ++k) {
            const int b = bg * 8 + k;
            const float e = swe[b];
            float4 v = *(const float4*)(pacc + (size_t)(c*K1B + b) * DIM + jbase);
            a.x += e*v.x; a.y += e*v.y; a.z += e*v.z; a.w += e*v.w;
        }
        sred[bg * 16 + col] = a;
        __syncthreads();
        if (tid < 16) {
            float4 o = make_float4(0.f, 0.f, 0.f, 0.f);
            #pragma unroll
            for (int gg = 0; gg < 16; ++gg) {
                float4 t = sred[gg * 16 + tid];
                o.x += t.x; o.y += t.y; o.z += t.z; o.w += t.w;
            }
            const float inv = 1.0f / (*szc);
            o.x *= inv; o.y *= inv; o.z *= inv; o.w *= inv;
            *(float4*)(g + c * DIM + jb * 64 + tid * 4) = o;
        }
    } else {
        // ---- select: per-cluster top-128 with exact ranks, all in LDS ----
        // Keys are unique (index tiebreak in low bits) so ranks are exact and
        // exactly TOPK winners exist.
        const int c = bid - 128;
        u64* lk = (u64*)shraw4;                              // 32 KB
        int* hist = (int*)(lk + NPER);                       // 16 KB
        unsigned short* cand = (unsigned short*)(hist + 4096); // 8 KB
        int* chunkSuf = (int*)(cand + NPER);                 // 1 KB
        int* critBin = chunkSuf + 256;
        int* candCnt = critBin + 1;

        for (int t = tid; t < NPER/2; t += 256)
            ((ull2*)lk)[t] = ((const ull2*)(keys + (size_t)c * NPER))[t];
        for (int t = tid; t < 4096; t += 256) hist[t] = 0;
        if (tid == 0) *candCnt = 0;
        __syncthreads();

        // histogram on key bits [63:52] (= top 12 bits of ordered float)
        #pragma unroll
        for (int q = 0; q < 16; ++q)
            atomicAdd(&hist[(int)(lk[tid + 256*q] >> 52)], 1);
        __syncthreads();

        {   // per-thread chunk sums (16 bins each)
            int s = 0;
            #pragma unroll
            for (int b = 0; b < 16; ++b) s += hist[tid*16 + b];
            chunkSuf[tid] = s;
        }
        __syncthreads();
        if (tid == 0) {   // serial suffix over 256 chunks (high->low)
            int run = 0;
            for (int t = 255; t >= 0; --t) {
                const int v = chunkSuf[t]; chunkSuf[t] = run; run += v;
            }
        }
        __syncthreads();
        {   // find critical bin B: above(B) < TOPK <= above(B)+hist[B]
            int run = chunkSuf[tid];             // keys in bins above my chunk
            for (int b = 15; b >= 0; --b) {
                const int bin = tid*16 + b;
                const int h = hist[bin];
                if (run < TOPK && run + h >= TOPK) *critBin = bin; // one hit
                run += h;
            }
        }
        __syncthreads();
        const int B = *critBin;

        // compact candidate set = all keys in bins >= B (winners are a subset)
        #pragma unroll
        for (int q = 0; q < 16; ++q) {
            const int i = tid + 256*q;
            if ((int)(lk[i] >> 52) >= B) {
                const int s = atomicAdd(candCnt, 1);
                cand[s] = (unsigned short)i;
            }
        }
        __syncthreads();

        // exact global rank by pairwise compare within candidate set
        // (keys below bin B cannot outrank any candidate). LDS reads at
        // wave-uniform addresses -> broadcast, conflict-free.
        const int M = *candCnt;
        for (int s = tid; s < M; s += 256) {
            const int i = (int)cand[s];
            const u64 ki = lk[i];
            int r = 0;
            for (int j = 0; j < M; ++j)
                r += (lk[(int)cand[j]] > ki) ? 1 : 0;
            if (r < TOPK) selIdx[c * TOPK + r] = i;
        }
    }
}

// ---------------- FAT B: blocks 0..127 = gather; 128..255 = k5_fusion ------
__global__ __launch_bounds__(256) void fat_b(
    const int* __restrict__ selIdx, const float* __restrict__ feats,
    float* __restrict__ out_sel,
    const float* __restrict__ v_w, const float* __restrict__ v_b,
    const float* __restrict__ g, float* __restrict__ fus)
{
    const int tid = threadIdx.x;
    if (blockIdx.x < 128) {
        // ---- gather: 8 ranked rows per block, software-pipelined copy ----
        const int c  = blockIdx.x >> 4;
        const int r0 = (blockIdx.x & 15) * 8;
        const float* fc = feats + (size_t)c * NPER * DIM;
        const int* sic = selIdx + c * TOPK + r0;

        f4 cur = __builtin_nontemporal_load(
            (const f4*)(fc + (size_t)sic[0] * DIM) + tid);
        #pragma unroll
        for (int s = 0; s < 8; ++s) {
            f4 nxt;
            if (s + 1 < 8)
                nxt = __builtin_nontemporal_load(
                    (const f4*)(fc + (size_t)sic[s+1] * DIM) + tid);
            __builtin_nontemporal_store(
                cur, (f4*)(out_sel + ((size_t)c * TOPK + r0 + s) * DIM) + tid);
            if (s + 1 < 8) cur = nxt;
        }
    } else {
        // ---- k5: fus = v_w @ g + v_b, one pass over v_w ----
        __shared__ float4 sg[NC][256];     // 32 KB
        const int lane = tid & 63, wave = tid >> 6;
        for (int t = tid; t < NC * 256; t += 256)
            ((float4*)sg)[t] = ((const float4*)g)[t];
        __syncthreads();

        const int row0 = (blockIdx.x - 128) * 8 + wave * 2;
        for (int rr = 0; rr < 2; ++rr) {
            const int o = row0 + rr;
            const float4* vr = (const float4*)(v_w + (size_t)o * DIM);
            float4 v[4];
            #pragma unroll
            for (int u = 0; u < 4; ++u) v[u] = vr[lane + 64*u];
            float p[NC];
            #pragma unroll
            for (int cc = 0; cc < NC; ++cc) {
                float s = 0.f;
                #pragma unroll
                for (int u = 0; u < 4; ++u) {
                    float4 gv = sg[cc][lane + 64*u];
                    s += v[u].x*gv.x + v[u].y*gv.y + v[u].z*gv.z + v[u].w*gv.w;
                }
                p[cc] = s;
            }
            #pragma unroll
            for (int off = 32; off > 0; off >>= 1) {
                #pragma unroll
                for (int cc = 0; cc < NC; ++cc) p[cc] += __shfl_xor(p[cc], off, 64);
            }
            if (lane == 0) {
                const float b = v_b[o];
                #pragma unroll
                for (int cc = 0; cc < NC; ++cc) fus[cc * DIM + o] = p[cc] + b;
            }
        }
    }
}

extern "C" void kernel_launch(void* const* d_in, const int* in_sizes, int n_in,
                              void* d_out, int out_size, void* d_ws, size_t ws_size,
                              hipStream_t stream) {
    const float* feats     = (const float*)d_in[0];
    const float* key_feats = (const float*)d_in[1];
    const float* q_w       = (const float*)d_in[2];
    const float* q_b       = (const float*)d_in[3];
    const float* v_w       = (const float*)d_in[4];
    const float* v_b       = (const float*)d_in[5];
    float* out      = (float*)d_out;
    float* out_sel  = out;
    float* out_fus  = out + (size_t)1024 * 1024;

    // workspace layout (8B-aligned first)
    u64*   keys   = (u64*)d_ws;                          // 256 KB
    float* pacc   = (float*)(keys + NC * NPER);          // 4 MB
    float* pm     = pacc + (size_t)NC * K1B * DIM;       // 1024
    float* pz     = pm + NC * K1B;                       // 1024
    float* g      = pz + NC * K1B;                       // 8*1024
    float* w_all  = g + NC * DIM;                        // 8*1024
    int*   selIdx = (int*)(w_all + NC * DIM);            // 8*128 ints = 4 KB

    k0_prep <<<dim3(NC * 4),  256, 0, stream>>>(key_feats, q_w, q_b, w_all);
    k1_main <<<dim3(K1B, NC), 256, 0, stream>>>(feats, w_all, keys, pacc, pm, pz);
    fat_a   <<<dim3(128 + NC), 256, 0, stream>>>(pacc, pm, pz, g, keys, selIdx);
    fat_b   <<<dim3(256),     256, 0, stream>>>(selIdx, feats, out_sel, v_w, v_b, g, out_fus);
}

// Round 4
// 232.794 us; speedup vs baseline: 1.3180x; 1.0203x over previous
//
#include <hip/hip_runtime.h>
#include <math.h>

// AdaptiveSelection on MI355X (gfx950)
// Inputs (fp32): cluster_features (8,4096,1024), key_feats (8,1,1024),
//                q_w (128,1024), q_b (128), v_w (1024,1024), v_b (1024)
// Outputs (fp32, concat): selected (1024,1024) then fus (8,1024)
//
// Algebra:
//   logit_i = f_i . w_c where w_c = q_w^T (q_w key_c + q_b)/sqrt(128) (+const, dropped)
//   topk-128 by logit == topk by softmax (monotone)
//   fusion = v_w @ (A^T feats) + v_b     (sum A = 1)
// Ranking: 64-bit sortable key (ordered float bits << 32 | ~index) makes the
// reference's (value desc, index asc) order a single unsigned compare.
// Top-128 via per-cluster in-LDS radix select (32KB keys fit in one block).
// R3 post-mortem: serial tid0 suffix scan in select was a 256-iter dependent
// LDS chain (~3-12us single-thread latency) -> parallel Hillis-Steele scan.
// fat_b widened to 512 blocks (gather 4 rows/block all-prefetched, k5 1 row/wave).
// Dispatches: k0 -> k1 -> fat_a(combine 128 | select 8) -> fat_b(gather 256|k5 256).

#define DIM   1024
#define NC    8
#define NPER  4096
#define QD    128
#define TOPK  128
#define K1B   128     // blocks per cluster in main streaming pass (4 blocks/CU)

typedef unsigned long long u64;
typedef __attribute__((ext_vector_type(2))) unsigned long long ull2;
typedef __attribute__((ext_vector_type(4))) float f4;   // for nontemporal ld/st

// ---------------- K0: fused prep -> w_all (8,1024) ----------------
__global__ __launch_bounds__(256) void k0_prep(
    const float* __restrict__ key_feats, const float* __restrict__ q_w,
    const float* __restrict__ q_b, float* __restrict__ w_all)
{
    const int c  = blockIdx.x >> 2, jc = blockIdx.x & 3;
    const int tid = threadIdx.x;
    __shared__ float part[256];
    __shared__ float qs[QD];

    {   // phase 1: qk[k] = dot(q_w[k], key_c) + q_b[k]; 2 threads per k
        const int k = tid >> 1, half = tid & 1;
        const float4* qr4 = (const float4*)(q_w + (size_t)k * DIM + half * 512);
        const float4* kf4 = (const float4*)(key_feats + (size_t)c * DIM + half * 512);
        float s = 0.f;
        #pragma unroll 16
        for (int j = 0; j < 128; ++j) {
            float4 a = qr4[j], b = kf4[j];
            s += a.x*b.x + a.y*b.y + a.z*b.z + a.w*b.w;
        }
        part[tid] = s;
    }
    __syncthreads();
    if (tid < QD) qs[tid] = part[2*tid] + part[2*tid+1] + q_b[tid];
    __syncthreads();

    // phase 2: w[j] = sum_k q_w[k][j] * qs[k] / sqrt(128)
    const int j = jc * 256 + tid;
    float s = 0.f;
    #pragma unroll 16
    for (int k = 0; k < QD; ++k)
        s += q_w[(size_t)k * DIM + j] * qs[k];
    w_all[c * DIM + j] = s * 0.08838834764831845f; // 1/sqrt(128)
}

// ---------------- K1: fused logits(keys) + online-softmax weighted row sum ----------
// feats stream via nontemporal loads (read-once; keep L2 for pacc/keys).
__global__ __launch_bounds__(256, 4) void k1_main(
    const float* __restrict__ feats, const float* __restrict__ w_all,
    u64* __restrict__ keys,            // (8,4096) sortable keys
    float* __restrict__ pacc,          // (8*K1B,1024)
    float* __restrict__ pm, float* __restrict__ pz)  // (8*K1B)
{
    const int c    = blockIdx.y;
    const int blk  = blockIdx.x;
    const int tid  = threadIdx.x;
    const int lane = tid & 63;
    const int wave = tid >> 6;

    const float4* w4 = (const float4*)(w_all + c * DIM);
    float4 wv[4];
    #pragma unroll
    for (int q = 0; q < 4; ++q) wv[q] = w4[lane + 64*q];

    float4 acc[4];
    #pragma unroll
    for (int q = 0; q < 4; ++q) acc[q] = make_float4(0.f, 0.f, 0.f, 0.f);
    float m = -INFINITY, Z = 0.f;

    const int wslot = blk * 4 + wave;          // 0..511
    const float* fc = feats + (size_t)c * NPER * DIM;

    f4 fA[4], fB[4];
    {
        const f4* f4p = (const f4*)(fc + (size_t)wslot * DIM);
        #pragma unroll
        for (int q = 0; q < 4; ++q) fA[q] = __builtin_nontemporal_load(f4p + lane + 64*q);
    }

    #define K1_PROCESS(FREG, ROW)                                              \
    do {                                                                       \
        float p = 0.f;                                                         \
        _Pragma("unroll")                                                      \
        for (int q = 0; q < 4; ++q)                                            \
            p += FREG[q].x*wv[q].x + FREG[q].y*wv[q].y +                       \
                 FREG[q].z*wv[q].z + FREG[q].w*wv[q].w;                        \
        _Pragma("unroll")                                                      \
        for (int off = 32; off > 0; off >>= 1) p += __shfl_xor(p, off, 64);    \
        if (lane == 0) {                                                       \
            unsigned int b = __float_as_uint(p);                               \
            unsigned int u = b ^ ((b & 0x80000000u) ? 0xFFFFFFFFu : 0x80000000u); \
            keys[c * NPER + (ROW)] = ((u64)u << 32) | (unsigned int)(~(ROW));  \
        }                                                                      \
        if (p > m) {   /* wave-uniform; rare after first rows */               \
            const float sOld = __expf(m - p);                                  \
            Z = Z * sOld + 1.f;                                                \
            _Pragma("unroll")                                                  \
            for (int q = 0; q < 4; ++q) {                                      \
                acc[q].x = acc[q].x * sOld + FREG[q].x;                        \
                acc[q].y = acc[q].y * sOld + FREG[q].y;                        \
                acc[q].z = acc[q].z * sOld + FREG[q].z;                        \
                acc[q].w = acc[q].w * sOld + FREG[q].w;                        \
            }                                                                  \
            m = p;                                                             \
        } else {                                                               \
            const float t = __expf(p - m);                                     \
            Z += t;                                                            \
            _Pragma("unroll")                                                  \
            for (int q = 0; q < 4; ++q) {                                      \
                acc[q].x += t * FREG[q].x;                                     \
                acc[q].y += t * FREG[q].y;                                     \
                acc[q].z += t * FREG[q].z;                                     \
                acc[q].w += t * FREG[q].w;                                     \
            }                                                                  \
        }                                                                      \
    } while (0)

    for (int it = 0; it < 8; it += 2) {
        const int r0 = wslot + 512 * it;
        {   // prefetch next row
            const f4* f4p = (const f4*)(fc + (size_t)(r0 + 512) * DIM);
            #pragma unroll
            for (int q = 0; q < 4; ++q) fB[q] = __builtin_nontemporal_load(f4p + lane + 64*q);
        }
        K1_PROCESS(fA, r0);
        if (it + 2 < 8) {
            const f4* f4p = (const f4*)(fc + (size_t)(r0 + 1024) * DIM);
            #pragma unroll
            for (int q = 0; q < 4; ++q) fA[q] = __builtin_nontemporal_load(f4p + lane + 64*q);
        }
        K1_PROCESS(fB, r0 + 512);
    }
    #undef K1_PROCESS

    __shared__ float sm[4], sz[4];
    __shared__ float sacc[4][DIM];
    if (lane == 0) { sm[wave] = m; sz[wave] = Z; }
    #pragma unroll
    for (int q = 0; q < 4; ++q)
        ((float4*)sacc[wave])[lane + 64*q] = acc[q];
    __syncthreads();

    const float mb = fmaxf(fmaxf(sm[0], sm[1]), fmaxf(sm[2], sm[3]));
    const float e0 = __expf(sm[0] - mb), e1 = __expf(sm[1] - mb);
    const float e2 = __expf(sm[2] - mb), e3 = __expf(sm[3] - mb);
    float4 a0 = ((float4*)sacc[0])[tid];
    float4 a1 = ((float4*)sacc[1])[tid];
    float4 a2 = ((float4*)sacc[2])[tid];
    float4 a3 = ((float4*)sacc[3])[tid];
    float4 o;
    o.x = a0.x*e0 + a1.x*e1 + a2.x*e2 + a3.x*e3;
    o.y = a0.y*e0 + a1.y*e1 + a2.y*e2 + a3.y*e3;
    o.z = a0.z*e0 + a1.z*e1 + a2.z*e2 + a3.z*e3;
    o.w = a0.w*e0 + a1.w*e1 + a2.w*e2 + a3.w*e3;
    ((float4*)(pacc + (size_t)(c * K1B + blk) * DIM))[tid] = o;
    if (tid == 0) {
        pm[c * K1B + blk] = mb;
        pz[c * K1B + blk] = sz[0]*e0 + sz[1]*e1 + sz[2]*e2 + sz[3]*e3;
    }
}

// ---------------- FAT A: blocks 0..127 = combine (16/cluster); 128..135 = select ----
__global__ __launch_bounds__(256) void fat_a(
    const float* __restrict__ pacc, const float* __restrict__ pm,
    const float* __restrict__ pz, float* __restrict__ g,
    const u64* __restrict__ keys, int* __restrict__ selIdx) // selIdx (8,128)
{
    const int bid = blockIdx.x;
    const int tid = threadIdx.x;
    // LDS overlay; select is the largest user (~57.4 KB)
    __shared__ float4 shraw4[3649];

    if (bid < 128) {
        // ---- combine: g_c[j] = (1/Z_c) sum_b swe[b] * pacc[c,b,j] ----
        const int c = bid >> 4, jb = bid & 15;         // 64 floats per block
        float* spm = (float*)shraw4;                   // 128
        float* spz = spm + 128;                        // 128
        float* swe = spz + 128;                        // 128
        float* szc = swe + 128;                        // 1 (+3 pad)
        float4* sred = (float4*)(szc + 4);             // [16 bg][16 col]

        if (tid < K1B)       spm[tid]       = pm[c*K1B + tid];
        else                 spz[tid - K1B] = pz[c*K1B + tid - K1B];
        __syncthreads();
        float mc = -INFINITY;
        for (int b = 0; b < K1B; ++b) mc = fmaxf(mc, spm[b]);
        if (tid < K1B) swe[tid] = __expf(spm[tid] - mc);
        __syncthreads();
        if (tid == 0) {
            float z = 0.f;
            for (int b = 0; b < K1B; ++b) z += spz[b] * swe[b];
            *szc = z;
        }
        const int col = tid & 15;       // float4 column within 64-float slice
        const int bg  = tid >> 4;       // 16 groups of 8 partials
        const int jbase = jb * 64 + col * 4;
        float4 a = make_float4(0.f, 0.f, 0.f, 0.f);
        #pragma unroll
        for (int k = 0; k < 8; ++k) {
            const int b = bg * 8 + k;
            const float e = swe[b];
            float4 v = *(const float4*)(pacc + (size_t)(c*K1B + b) * DIM + jbase);
            a.x += e*v.x; a.y += e*v.y; a.z += e*v.z; a.w += e*v.w;
        }
        sred[bg * 16 + col] = a;
        __syncthreads();
        if (tid < 16) {
            float4 o = make_float4(0.f, 0.f, 0.f, 0.f);
            #pragma unroll
            for (int gg = 0; gg < 16; ++gg) {
                float4 t = sred[gg * 16 + tid];
                o.x += t.x; o.y += t.y; o.z += t.z; o.w += t.w;
            }
            const float inv = 1.0f / (*szc);
            o.x *= inv; o.y *= inv; o.z *= inv; o.w *= inv;
            *(float4*)(g + c * DIM + jb * 64 + tid * 4) = o;
        }
    } else {
        // ---- select: per-cluster top-128 with exact ranks, all in LDS ----
        // Keys are unique (index tiebreak in low bits) so ranks are exact and
        // exactly TOPK winners exist.
        const int c = bid - 128;
        u64* lk = (u64*)shraw4;                              // 32 KB
        int* hist = (int*)(lk + NPER);                       // 16 KB
        unsigned short* cand = (unsigned short*)(hist + 4096); // 8 KB
        int* chunkSuf = (int*)(cand + NPER);                 // 1 KB
        int* critBin = chunkSuf + 256;
        int* candCnt = critBin + 1;

        for (int t = tid; t < NPER/2; t += 256)
            ((ull2*)lk)[t] = ((const ull2*)(keys + (size_t)c * NPER))[t];
        for (int t = tid; t < 4096; t += 256) hist[t] = 0;
        if (tid == 0) *candCnt = 0;
        __syncthreads();

        // histogram on key bits [63:52] (= top 12 bits of ordered float)
        #pragma unroll
        for (int q = 0; q < 16; ++q)
            atomicAdd(&hist[(int)(lk[tid + 256*q] >> 52)], 1);
        __syncthreads();

        int myChunk;   // this thread's 16-bin chunk total
        {
            int s = 0;
            #pragma unroll
            for (int b = 0; b < 16; ++b) s += hist[tid*16 + b];
            myChunk = s;
            chunkSuf[tid] = s;
        }
        __syncthreads();
        // parallel inclusive suffix sum over 256 chunk totals (Hillis-Steele)
        #pragma unroll
        for (int d = 1; d < 256; d <<= 1) {
            const int add = (tid + d < 256) ? chunkSuf[tid + d] : 0;
            __syncthreads();
            chunkSuf[tid] += add;
            __syncthreads();
        }
        {   // find critical bin B: above(B) < TOPK <= above(B)+hist[B]
            int run = chunkSuf[tid] - myChunk;   // keys in bins above my chunk
            for (int b = 15; b >= 0; --b) {
                const int bin = tid*16 + b;
                const int h = hist[bin];
                if (run < TOPK && run + h >= TOPK) *critBin = bin; // one hit
                run += h;
            }
        }
        __syncthreads();
        const int B = *critBin;

        // compact candidate set = all keys in bins >= B (winners are a subset)
        #pragma unroll
        for (int q = 0; q < 16; ++q) {
            const int i = tid + 256*q;
            if ((int)(lk[i] >> 52) >= B) {
                const int s = atomicAdd(candCnt, 1);
                cand[s] = (unsigned short)i;
            }
        }
        __syncthreads();

        // exact global rank by pairwise compare within candidate set
        // (keys below bin B cannot outrank any candidate). LDS reads at
        // wave-uniform addresses -> broadcast, conflict-free. Rank result is
        // independent of cand[] ordering (set semantics).
        const int M = *candCnt;
        for (int s = tid; s < M; s += 256) {
            const int i = (int)cand[s];
            const u64 ki = lk[i];
            int r = 0;
            for (int j = 0; j < M; ++j)
                r += (lk[(int)cand[j]] > ki) ? 1 : 0;
            if (r < TOPK) selIdx[c * TOPK + r] = i;
        }
    }
}

// ---------------- FAT B: blocks 0..255 = gather; 256..511 = k5_fusion ------
__global__ __launch_bounds__(256) void fat_b(
    const int* __restrict__ selIdx, const float* __restrict__ feats,
    float* __restrict__ out_sel,
    const float* __restrict__ v_w, const float* __restrict__ v_b,
    const float* __restrict__ g, float* __restrict__ fus)
{
    const int tid = threadIdx.x;
    if (blockIdx.x < 256) {
        // ---- gather: 4 ranked rows per block, all loads issued before stores ----
        const int c  = blockIdx.x >> 5;
        const int r0 = (blockIdx.x & 31) * 4;
        const float* fc = feats + (size_t)c * NPER * DIM;
        const int* sic = selIdx + c * TOPK + r0;
        const int i0 = sic[0], i1 = sic[1], i2 = sic[2], i3 = sic[3];

        f4 a0 = __builtin_nontemporal_load((const f4*)(fc + (size_t)i0 * DIM) + tid);
        f4 a1 = __builtin_nontemporal_load((const f4*)(fc + (size_t)i1 * DIM) + tid);
        f4 a2 = __builtin_nontemporal_load((const f4*)(fc + (size_t)i2 * DIM) + tid);
        f4 a3 = __builtin_nontemporal_load((const f4*)(fc + (size_t)i3 * DIM) + tid);
        f4* dst = (f4*)(out_sel + ((size_t)c * TOPK + r0) * DIM) + tid;
        __builtin_nontemporal_store(a0, dst);
        __builtin_nontemporal_store(a1, dst + 256);
        __builtin_nontemporal_store(a2, dst + 512);
        __builtin_nontemporal_store(a3, dst + 768);
    } else {
        // ---- k5: fus = v_w @ g + v_b; 4 rows per block, 1 row per wave ----
        __shared__ float4 sg[NC][256];     // 32 KB
        const int lane = tid & 63, wave = tid >> 6;
        for (int t = tid; t < NC * 256; t += 256)
            ((float4*)sg)[t] = ((const float4*)g)[t];
        __syncthreads();

        const int o = (blockIdx.x - 256) * 4 + wave;
        const float4* vr = (const float4*)(v_w + (size_t)o * DIM);
        float4 v[4];
        #pragma unroll
        for (int u = 0; u < 4; ++u) v[u] = vr[lane + 64*u];
        float p[NC];
        #pragma unroll
        for (int cc = 0; cc < NC; ++cc) {
            float s = 0.f;
            #pragma unroll
            for (int u = 0; u < 4; ++u) {
                float4 gv = sg[cc][lane + 64*u];
                s += v[u].x*gv.x + v[u].y*gv.y + v[u].z*gv.z + v[u].w*gv.w;
            }
            p[cc] = s;
        }
        #pragma unroll
        for (int off = 32; off > 0; off >>= 1) {
            #pragma unroll
            for (int cc = 0; cc < NC; ++cc) p[cc] += __shfl_xor(p[cc], off, 64);
        }
        if (lane == 0) {
            const float b = v_b[o];
            #pragma unroll
            for (int cc = 0; cc < NC; ++cc) fus[cc * DIM + o] = p[cc] + b;
        }
    }
}

extern "C" void kernel_launch(void* const* d_in, const int* in_sizes, int n_in,
                              void* d_out, int out_size, void* d_ws, size_t ws_size,
                              hipStream_t stream) {
    const float* feats     = (const float*)d_in[0];
    const float* key_feats = (const float*)d_in[1];
    const float* q_w       = (const float*)d_in[2];
    const float* q_b       = (const float*)d_in[3];
    const float* v_w       = (const float*)d_in[4];
    const float* v_b       = (const float*)d_in[5];
    float* out      = (float*)d_out;
    float* out_sel  = out;
    float* out_fus  = out + (size_t)1024 * 1024;

    // workspace layout (8B-aligned first)
    u64*   keys   = (u64*)d_ws;                          // 256 KB
    float* pacc   = (float*)(keys + NC * NPER);          // 4 MB
    float* pm     = pacc + (size_t)NC * K1B * DIM;       // 1024
    float* pz     = pm + NC * K1B;                       // 1024
    float* g      = pz + NC * K1B;                       // 8*1024
    float* w_all  = g + NC * DIM;                        // 8*1024
    int*   selIdx = (int*)(w_all + NC * DIM);            // 8*128 ints = 4 KB

    k0_prep <<<dim3(NC * 4),   256, 0, stream>>>(key_feats, q_w, q_b, w_all);
    k1_main <<<dim3(K1B, NC),  256, 0, stream>>>(feats, w_all, keys, pacc, pm, pz);
    fat_a   <<<dim3(128 + NC), 256, 0, stream>>>(pacc, pm, pz, g, keys, selIdx);
    fat_b   <<<dim3(512),      256, 0, stream>>>(selIdx, feats, out_sel, v_w, v_b, g, out_fus);
}